// Round 9
// baseline (267.597 us; speedup 1.0000x reference)
//
#include <hip/hip_runtime.h>

#define T_STEPS 60
#define HID 128
#define ROWS 32
#define NBLK (16384 / ROWS)  // 512 blocks

typedef __attribute__((ext_vector_type(8))) short short8;
typedef __attribute__((ext_vector_type(4))) float f32x4;

#define K1 1.44269504088896340736f  // log2(e)

__device__ __forceinline__ unsigned short f2bf(float f) {
  unsigned u = __float_as_uint(f);
  return (unsigned short)((u + 0x7fffu + ((u >> 16) & 1u)) >> 16);
}
__device__ __forceinline__ float sigm(float x) {
  return __builtin_amdgcn_rcpf(1.0f + __expf(-x));
}

// LDS map (bytes):
//   [0,8192):        h buffer 0 (32 rows x 128 units bf16, row r at r*256, swizzled)
//   [8192,16384):    h buffer 1
//   [16384,17408):   decode partials buf0: [8 waves][32 rows] f32
//   [17408,18432):   decode partials buf1
//   [18432,26112):   out staging: [32 rows][60 t] f32
#define HB0 0
#define HB1 8192
#define PT0 16384
#define PT1 17408
#define OUT_BASE 18432
#define LDS_BYTES 26112

__global__ __launch_bounds__(512, 2) void lstm_fused(
    const float* __restrict__ x, const float* __restrict__ W_enc,
    const float* __restrict__ b_enc, const float* __restrict__ W_ih,
    const float* __restrict__ W_hh, const float* __restrict__ b_ih,
    const float* __restrict__ b_hh, const float* __restrict__ W_dec,
    const float* __restrict__ b_dec, float* __restrict__ out) {
  __shared__ __align__(16) unsigned char lds[LDS_BYTES];

  const int tid = threadIdx.x;
  const int wav = tid >> 6;
  const int lane = tid & 63;
  const int l15 = lane & 15;
  const int l4 = lane >> 4;
  const int u = wav * 16 + l15;        // hidden unit owned by this lane
  const int row0 = blockIdx.x * ROWS;  // global batch row base
  float* outf = (float*)(lds + OUT_BASE);

  // zero h buf0 (8192 B)
  for (int i = tid; i < 2048; i += 512) ((unsigned*)(lds + HB0))[i] = 0u;

  // ---- xp = enc @ W_ih^T + b_ih + b_hh, f32 IN REGISTERS (two chains) ----
  // (f16/LDS xp was the R3/R5 failure; must stay f32.)
  float xpa[4][4], xpb[4][4];
  {
    float xa0[4], xa1[4], xa2[4], xb0[4], xb1[4], xb2[4];
#pragma unroll
    for (int v = 0; v < 4; ++v) {
      int r = 4 * l4 + v;
      const float* pa = x + (size_t)(row0 + r) * 3;
      const float* pb = x + (size_t)(row0 + 16 + r) * 3;
      xa0[v] = pa[0]; xa1[v] = pa[1]; xa2[v] = pa[2];
      xb0[v] = pb[0]; xb1[v] = pb[1]; xb2[v] = pb[2];
    }
#pragma unroll
    for (int gt = 0; gt < 4; ++gt) {
      float bias = b_ih[gt * 128 + u] + b_hh[gt * 128 + u];
#pragma unroll
      for (int v = 0; v < 4; ++v) { xpa[gt][v] = bias; xpb[gt][v] = bias; }
    }
    const f32x4* wr0 = (const f32x4*)(W_ih + (size_t)u * 64);
    const f32x4* wr1 = (const f32x4*)(W_ih + (size_t)(128 + u) * 64);
    const f32x4* wr2 = (const f32x4*)(W_ih + (size_t)(256 + u) * 64);
    const f32x4* wr3 = (const f32x4*)(W_ih + (size_t)(384 + u) * 64);
    for (int e4 = 0; e4 < 16; ++e4) {
      f32x4 w0 = wr0[e4], w1 = wr1[e4], w2 = wr2[e4], w3 = wr3[e4];
#pragma unroll
      for (int j = 0; j < 4; ++j) {
        int e = e4 * 4 + j;
        float we0 = W_enc[e * 3], we1 = W_enc[e * 3 + 1], we2 = W_enc[e * 3 + 2];
        float be = b_enc[e];
#pragma unroll
        for (int v = 0; v < 4; ++v) {
          float ea = fmaf(we0, xa0[v], fmaf(we1, xa1[v], fmaf(we2, xa2[v], be)));
          float eb = fmaf(we0, xb0[v], fmaf(we1, xb1[v], fmaf(we2, xb2[v], be)));
          xpa[0][v] = fmaf(w0[j], ea, xpa[0][v]);
          xpa[1][v] = fmaf(w1[j], ea, xpa[1][v]);
          xpa[2][v] = fmaf(w2[j], ea, xpa[2][v]);
          xpa[3][v] = fmaf(w3[j], ea, xpa[3][v]);
          xpb[0][v] = fmaf(w0[j], eb, xpb[0][v]);
          xpb[1][v] = fmaf(w1[j], eb, xpb[1][v]);
          xpb[2][v] = fmaf(w2[j], eb, xpb[2][v]);
          xpb[3][v] = fmaf(w3[j], eb, xpb[3][v]);
        }
      }
    }
#pragma unroll
    for (int gt = 0; gt < 4; ++gt) {
      float s = (gt == 2) ? (-2.0f * K1) : (-K1);
#pragma unroll
      for (int v = 0; v < 4; ++v) { xpa[gt][v] *= s; xpb[gt][v] *= s; }
    }
  }

  // ---- W_hh bf16 B-fragments, prescaled into exp2 domain (shared by chains) ----
  short8 bw[4][4];
#pragma unroll
  for (int gt = 0; gt < 4; ++gt) {
    float s = (gt == 2) ? (-2.0f * K1) : (-K1);
#pragma unroll
    for (int kt = 0; kt < 4; ++kt) {
      const float* p = W_hh + (size_t)(gt * 128 + u) * HID + kt * 32 + 8 * l4;
      short8 f;
#pragma unroll
      for (int j = 0; j < 8; ++j) f[j] = (short)f2bf(s * p[j]);
      bw[gt][kt] = f;
    }
  }

  float cta[4], ctb[4];
#pragma unroll
  for (int v = 0; v < 4; ++v) { cta[v] = 0.0f; ctb[v] = 0.0f; }

  // ---- LDS addresses (swizzle bits 4-6; row+16 adds bit 12 -> same swizzle) ----
  const unsigned swzA =
      (((unsigned)(l15 & 7)) << 4) ^ (((unsigned)(l15 & 8)) << 2);
  unsigned rdA[4];
#pragma unroll
  for (int kt = 0; kt < 4; ++kt)
    rdA[kt] = ((unsigned)(l15 * 256 + l4 * 16 + kt * 64)) ^ swzA;
  unsigned wrA[4];
#pragma unroll
  for (int v = 0; v < 4; ++v) {
    unsigned rr = (unsigned)(4 * l4 + v);
    wrA[v] = (rr * 256 + (unsigned)u * 2) ^ ((rr & 7u) << 4) ^ ((rr & 8u) << 2);
  }
  const unsigned ptW = (unsigned)(wav * 32 + 4 * l4) * 4;  // partials write slot
  const float wdu = W_dec[u];
  const float kneg = -2.0f * K1;
  const float kpos = 2.0f * K1;

  __syncthreads();

  // gate math in exp2 domain (verified R7):
  //   e^{-i}=2^acc0, e^{-f}=2^acc1, e^{-2g}=2^acc2, e^{-o}=2^acc3
  //   ct' = [ct*A*G + k(1-eg)*F] / (F*A*G),  k=-2log2e;  h=(1-ec)/(Bo*(1+ec))
#define ACT(ACC, CT, H)                                                        \
  {                                                                            \
    float ea = __builtin_amdgcn_exp2f(ACC[0][vv]);                             \
    float ef = __builtin_amdgcn_exp2f(ACC[1][vv]);                             \
    float eg = __builtin_amdgcn_exp2f(ACC[2][vv]);                             \
    float eo = __builtin_amdgcn_exp2f(ACC[3][vv]);                             \
    float A = 1.0f + ea, F = 1.0f + ef, G = 1.0f + eg, Bo = 1.0f + eo;         \
    float AG = A * G;                                                          \
    float r = __builtin_amdgcn_rcpf(F * AG);                                   \
    float tt = fmaf(kpos, eg, kneg);                                           \
    float num = fmaf(CT[vv], AG, tt * F);                                      \
    float cn = num * r;                                                        \
    CT[vv] = cn;                                                               \
    float ec = __builtin_amdgcn_exp2f(cn);                                     \
    float r2 = __builtin_amdgcn_rcpf(Bo * (1.0f + ec));                        \
    H = (1.0f - ec) * r2;                                                      \
  }

#define STEP(RB, WB, PW, PR, tcur)                                             \
  {                                                                            \
    /* duty: tree-sum previous step's decode partials (1 wave, lanes 0-31) */  \
    if ((tcur) > 0 && wav == (((tcur)-1) & 7) && lane < 32) {                  \
      float s = 0.0f;                                                          \
      _Pragma("unroll") for (int w = 0; w < 8; ++w)                            \
          s += *(const float*)(lds + (PR) + (unsigned)(w * 32 + lane) * 4);    \
      outf[lane * T_STEPS + ((tcur)-1)] = s;                                   \
    }                                                                          \
    f32x4 acca[4], accb[4];                                                    \
    _Pragma("unroll") for (int gt = 0; gt < 4; ++gt) {                         \
      _Pragma("unroll") for (int v = 0; v < 4; ++v) {                          \
        acca[gt][v] = xpa[gt][v];                                              \
        accb[gt][v] = xpb[gt][v];                                              \
      }                                                                        \
    }                                                                          \
    _Pragma("unroll") for (int kt = 0; kt < 4; ++kt) {                         \
      short8 afa = *(const short8*)(lds + (RB) + rdA[kt]);                     \
      short8 afb = *(const short8*)(lds + (RB) + 4096 + rdA[kt]);              \
      _Pragma("unroll") for (int gt = 0; gt < 4; ++gt) {                       \
        acca[gt] = __builtin_amdgcn_mfma_f32_16x16x32_bf16(afa, bw[gt][kt],    \
                                                           acca[gt], 0, 0, 0); \
        accb[gt] = __builtin_amdgcn_mfma_f32_16x16x32_bf16(afb, bw[gt][kt],    \
                                                           accb[gt], 0, 0, 0); \
      }                                                                        \
    }                                                                          \
    f32x4 pza, pzb;                                                            \
    _Pragma("unroll") for (int vv = 0; vv < 4; ++vv) {                         \
      float ha, hb;                                                            \
      ACT(acca, cta, ha)                                                       \
      ACT(accb, ctb, hb)                                                       \
      *(unsigned short*)(lds + (WB) + wrA[vv]) = f2bf(ha);                     \
      *(unsigned short*)(lds + (WB) + 4096 + wrA[vv]) = f2bf(hb);              \
      pza[vv] = ha * wdu;                                                      \
      pzb[vv] = hb * wdu;                                                      \
    }                                                                          \
    _Pragma("unroll") for (int vv = 0; vv < 4; ++vv) {                         \
      pza[vv] += __shfl_xor(pza[vv], 1, 64);                                   \
      pzb[vv] += __shfl_xor(pzb[vv], 1, 64);                                   \
      pza[vv] += __shfl_xor(pza[vv], 2, 64);                                   \
      pzb[vv] += __shfl_xor(pzb[vv], 2, 64);                                   \
      pza[vv] += __shfl_xor(pza[vv], 4, 64);                                   \
      pzb[vv] += __shfl_xor(pzb[vv], 4, 64);                                   \
      pza[vv] += __shfl_xor(pza[vv], 8, 64);                                   \
      pzb[vv] += __shfl_xor(pzb[vv], 8, 64);                                   \
    }                                                                          \
    if (l15 == 0) {                                                            \
      *(f32x4*)(lds + (PW) + ptW) = pza;                                       \
      *(f32x4*)(lds + (PW) + 64 + ptW) = pzb;                                  \
    }                                                                          \
    __syncthreads();                                                           \
  }

  for (int t = 0; t < T_STEPS; t += 2) {
    STEP(HB0, HB1, PT0, PT1, t)
    STEP(HB1, HB0, PT1, PT0, t + 1)
  }
#undef STEP
#undef ACT

  // drain decode for t=59 (partials in PT1, written before last barrier)
  if (wav == ((T_STEPS - 1) & 7) && lane < 32) {
    float s = 0.0f;
#pragma unroll
    for (int w = 0; w < 8; ++w)
      s += *(const float*)(lds + PT1 + (unsigned)(w * 32 + lane) * 4);
    outf[lane * T_STEPS + (T_STEPS - 1)] = s;
  }
  __syncthreads();

  // ---- epilogue: sigmoid + coalesced store (32 rows x 15 float4 chunks) ----
  const float bdec = b_dec[0];
  if (tid < 480) {
    int r = tid / 15, c4 = tid - r * 15;
    f32x4 s = *(const f32x4*)&outf[r * T_STEPS + c4 * 4];
    f32x4 o;
#pragma unroll
    for (int k = 0; k < 4; ++k) o[k] = sigm(s[k] + bdec);
    *(f32x4*)(out + (size_t)(row0 + r) * T_STEPS + c4 * 4) = o;
  }
}

extern "C" void kernel_launch(void* const* d_in, const int* in_sizes, int n_in,
                              void* d_out, int out_size, void* d_ws, size_t ws_size,
                              hipStream_t stream) {
  const float* x = (const float*)d_in[0];
  const float* W_enc = (const float*)d_in[1];
  const float* b_enc = (const float*)d_in[2];
  const float* W_ih = (const float*)d_in[3];
  const float* W_hh = (const float*)d_in[4];
  const float* b_ih = (const float*)d_in[5];
  const float* b_hh = (const float*)d_in[6];
  const float* W_dec = (const float*)d_in[7];
  const float* b_dec = (const float*)d_in[8];
  float* out = (float*)d_out;

  dim3 grid(NBLK);  // 512 blocks x 32 rows
  dim3 block(512);
  lstm_fused<<<grid, block, 0, stream>>>(x, W_enc, b_enc, W_ih, W_hh, b_ih, b_hh,
                                         W_dec, b_dec, out);
}